// Round 5
// baseline (213.663 us; speedup 1.0000x reference)
//
#include <hip/hip_runtime.h>
#include <cstdint>
#include <cstddef>

typedef unsigned long long u64;

// ---------------- problem constants ----------------
constexpr int Bn   = 8;
constexpr int Pn   = 2000;
constexpr int Cn   = 81;
constexpr int CM1  = 80;
constexpr int Mn   = Pn * CM1;      // 160000 per image
constexpr int KPRE = 2048;
constexpr int NDET = 100;
constexpr int NSEC = 16;            // sections per image
constexpr int SPROP = Pn / NSEC;    // 125 proposals per section
constexpr int SECEL = SPROP * CM1;  // 10000 elements per section
constexpr int CBUF = 4096;          // section LDS buffer (max valid = 125*19 = 2375)
constexpr float W_IMG = 1333.0f;
constexpr float H_IMG = 800.0f;
constexpr float XFORM_CLIP = 4.135166556742356f; // log(1000/16)
constexpr float NMS_OFF = 1334.0f;               // max(W,H)+1

// ---------------- ws layout (bytes); everything written before read ----------
constexpr size_t OFF_KEYS  = 0;                                    // Bn*Mn u64 (10.24 MB)
constexpr size_t OFF_SLIST = OFF_KEYS + (size_t)Bn * Mn * 8;       // Bn*NSEC*KPRE u64 (2 MB)
constexpr size_t OFF_SCNT  = OFF_SLIST + (size_t)Bn * NSEC * KPRE * 8; // Bn*NSEC int

__device__ __forceinline__ void decode_clip(const float4 rv, float w, float h,
                                            float cx, float cy, float out[4]) {
  float dx = rv.x / 10.0f;
  float dy = rv.y / 10.0f;
  float dw = fminf(rv.z / 5.0f, XFORM_CLIP);
  float dh = fminf(rv.w / 5.0f, XFORM_CLIP);
  float pcx = dx * w + cx;
  float pcy = dy * h + cy;
  float pw = expf(dw) * w;
  float ph = expf(dh) * h;
  out[0] = fminf(fmaxf(pcx - 0.5f * pw, 0.0f), W_IMG);
  out[1] = fminf(fmaxf(pcy - 0.5f * ph, 0.0f), H_IMG);
  out[2] = fminf(fmaxf(pcx + 0.5f * pw, 0.0f), W_IMG);
  out[3] = fminf(fmaxf(pcy + 0.5f * ph, 0.0f), H_IMG);
}

// ---------------- K1: softmax + decode + validity -> key array ----------------
__global__ __launch_bounds__(256) void
k1_score(const float* __restrict__ logits, const float* __restrict__ reg,
         const float* __restrict__ props, u64* __restrict__ keys) {
  int wid = blockIdx.x * 4 + (threadIdx.x >> 6);   // proposal id (b*Pn+p), grid exact
  int lane = threadIdx.x & 63;
  int b = wid / Pn, p = wid % Pn;

  const float* lg = logits + (size_t)wid * Cn;
  float x0 = lg[lane];
  float x1 = (lane < Cn - 64) ? lg[64 + lane] : -3.4e38f;
  float mx = fmaxf(x0, x1);
  for (int m = 32; m; m >>= 1) mx = fmaxf(mx, __shfl_xor(mx, m, 64));
  float e0 = expf(x0 - mx);
  float e1 = (lane < Cn - 64) ? expf(x1 - mx) : 0.0f;
  float ssum = e0 + e1;
  for (int m = 32; m; m >>= 1) ssum += __shfl_xor(ssum, m, 64);

  const float4 pb = *reinterpret_cast<const float4*>(props + (size_t)wid * 4);
  float w = pb.z - pb.x, h = pb.w - pb.y;
  float cx = pb.x + 0.5f * w, cy = pb.y + 0.5f * h;

  const float* rrow = reg + (size_t)wid * (Cn * 4);
  u64* krow = keys + (size_t)b * Mn + (size_t)p * CM1;

  #pragma unroll
  for (int slot = 0; slot < 2; slot++) {
    int c = lane + slot * 64;
    float e = slot ? e1 : e0;
    if (c < 1 || c >= Cn) continue;
    float sc = e / ssum;
    float4 rv = *reinterpret_cast<const float4*>(rrow + c * 4);
    float bx[4];
    decode_clip(rv, w, h, cx, cy, bx);
    bool valid = (sc > 0.05f) && (bx[2] - bx[0] >= 0.01f) && (bx[3] - bx[1] >= 0.01f);
    unsigned m = (unsigned)(p * CM1 + (c - 1));
    u64 key = valid ? (((u64)__float_as_uint(sc) << 32) | (0xFFFFFFFFu - m)) : 0ull;
    krow[c - 1] = key;
  }
}

// ---------------- K2: per-section compact + bitonic sort -> sorted list -------
__global__ __launch_bounds__(256) void
k2_section(const u64* __restrict__ keys, u64* __restrict__ slist,
           int* __restrict__ scnt) {
  int blk = blockIdx.x, t = threadIdx.x, lane = t & 63, w = t >> 6;
  int b = blk >> 4, s = blk & 15;
  __shared__ u64 cbuf[CBUF];   // 32 KB
  __shared__ int wc[4];
  const u64* kb = keys + (size_t)b * Mn + (size_t)s * SECEL;

  int base = 0;
  for (int it = 0; it < 10; it++) {
    int i0 = it * 1024 + t * 4;
    u64 k0 = 0, k1 = 0, k2 = 0, k3 = 0;
    if (i0 + 3 < SECEL) {
      k0 = kb[i0]; k1 = kb[i0 + 1]; k2 = kb[i0 + 2]; k3 = kb[i0 + 3];
    } else {
      if (i0     < SECEL) k0 = kb[i0];
      if (i0 + 1 < SECEL) k1 = kb[i0 + 1];
      if (i0 + 2 < SECEL) k2 = kb[i0 + 2];
      if (i0 + 3 < SECEL) k3 = kb[i0 + 3];
    }
    int myc = (k0 != 0) + (k1 != 0) + (k2 != 0) + (k3 != 0);
    int incl = myc;
    for (int sh = 1; sh < 64; sh <<= 1) {
      int y = __shfl_up(incl, sh, 64);
      if (lane >= sh) incl += y;
    }
    if (lane == 63) wc[w] = incl;
    __syncthreads();
    int pos = base + (incl - myc);
    for (int q = 0; q < w; q++) pos += wc[q];
    int tot = wc[0] + wc[1] + wc[2] + wc[3];
    if (k0) cbuf[pos++] = k0;
    if (k1) cbuf[pos++] = k1;
    if (k2) cbuf[pos++] = k2;
    if (k3) cbuf[pos++] = k3;
    base += tot;
    __syncthreads();
  }
  int n = base;                 // section candidate count (<= 2375)
  int npow = 2;
  while (npow < n) npow <<= 1;
  for (int i = n + t; i < npow; i += 256) cbuf[i] = 0ull;
  __syncthreads();
  for (int k = 2; k <= npow; k <<= 1) {
    for (int j = k >> 1; j > 0; j >>= 1) {
      for (int i = t; i < npow; i += 256) {
        int ixj = i ^ j;
        if (ixj > i) {
          u64 a = cbuf[i], c2 = cbuf[ixj];
          bool dir = ((i & k) == 0);  // descending overall
          if ((a < c2) == dir) { cbuf[i] = c2; cbuf[ixj] = a; }
        }
      }
      __syncthreads();
    }
  }
  int outn = min(n, KPRE);
  u64* dst = slist + (size_t)blk * KPRE;
  for (int i = t; i < outn; i += 256) dst[i] = cbuf[i];
  if (t == 0) scnt[blk] = outn;
}

// decode a candidate key into raw clipped box + label + score
__device__ __forceinline__ void key_decode(u64 key, int b,
                                           const float* __restrict__ reg,
                                           const float* __restrict__ props,
                                           float bx[4], int& label, float& sc) {
  sc = __uint_as_float((unsigned)(key >> 32));
  bx[0] = bx[1] = bx[2] = bx[3] = 0.0f;
  label = 0;
  if (key != 0ull) {
    int m = (int)(0xFFFFFFFFu - (unsigned)key);
    int p = m / CM1;
    int c = m - p * CM1 + 1;
    int nidx = b * Pn + p;
    const float4 pb = *reinterpret_cast<const float4*>(props + (size_t)nidx * 4);
    float w = pb.z - pb.x, h = pb.w - pb.y;
    float cx = pb.x + 0.5f * w, cy = pb.y + 0.5f * h;
    float4 rv = *reinterpret_cast<const float4*>(reg + (size_t)nidx * (Cn * 4) + c * 4);
    decode_clip(rv, w, h, cx, cy, bx);
    label = c;
  }
}

// ---------------- K3: merge 16 section lists -> top-2048 -> NMS -> output ----
// One 256-thread block per image. Sequential truncated merge-path merges are
// exact: any global-top-2048 element is in its section top-2048 and survives
// every truncation (inductive subset argument).
__global__ __launch_bounds__(256) void
k3_merge_nms(const u64* __restrict__ slist, const int* __restrict__ scnt,
             const float* __restrict__ reg, const float* __restrict__ props,
             float* __restrict__ out) {
  int b = blockIdx.x, t = threadIdx.x, lane = t & 63, w = t >> 6;
  __shared__ u64 accK[KPRE];                       // 16 KB
  __shared__ __align__(16) char smemraw[32768];    // Lbuf (merge) / obox (NMS)
  __shared__ u64 maskb[256][4];                    // 8 KB
  __shared__ u64 keepw[KPRE / 64];                 // 256 B
  __shared__ int acc[NDET];
  __shared__ int kcnt_sh;
  u64* L = (u64*)smemraw;
  float4* obox = (float4*)smemraw;

  // ---- phase A: sequential truncated merges ----
  int alen = scnt[b * NSEC];
  {
    const u64* S0 = slist + (size_t)(b * NSEC) * KPRE;
    for (int i = t; i < KPRE; i += 256) accK[i] = (i < alen) ? S0[i] : 0ull;
  }
  __syncthreads();
  for (int s2 = 1; s2 < NSEC; s2++) {
    int nB = scnt[b * NSEC + s2];
    const u64* B = slist + (size_t)(b * NSEC + s2) * KPRE;
    for (int i = t; i < nB; i += 256) L[i] = B[i];
    __syncthreads();
    int outLen = min(KPRE, alen + nB);
    int d = t * 8;
    u64 rg[8];
    int cnt = 0;
    if (d < outLen) {
      int lo = max(0, d - nB), hi = min(d, alen);
      while (lo < hi) {
        int mid = (lo + hi) >> 1;
        if (accK[mid] >= L[d - 1 - mid]) lo = mid + 1; else hi = mid;
      }
      int i = lo, j = d - lo;
      for (int e = 0; e < 8 && d + e < outLen; e++) {
        u64 v;
        if (j >= nB || (i < alen && accK[i] >= L[j])) v = accK[i++];
        else v = L[j++];
        rg[cnt++] = v;
      }
    }
    __syncthreads();           // all reads done before in-place writes
    for (int e = 0; e < cnt; e++) accK[d + e] = rg[e];
    alen = outLen;
    __syncthreads();
  }
  for (int i = alen + t; i < KPRE; i += 256) accK[i] = 0ull;
  __syncthreads();

  // ---- phase B: decode boxes into LDS (reuses merge buffer) ----
  #pragma unroll
  for (int s = 0; s < 8; s++) {
    int j = t + s * 256;
    u64 key = accK[j];
    float bx[4]; int label; float sc;
    key_decode(key, b, reg, props, bx, label, sc);
    float off = (float)label * NMS_OFF;
    obox[j] = make_float4(bx[0] + off, bx[1] + off, bx[2] + off, bx[3] + off);
    u64 bal = __ballot(key != 0ull);
    if (lane == 0) keepw[s * 4 + w] = bal;
  }
  __syncthreads();

  // ---- phase C: windowed bitmask greedy NMS with early exit ----
  int kcount = 0;
  for (int w0 = 0; w0 < KPRE && kcount < NDET; w0 += 256) {
    // step1: suppress window cols by previously accepted boxes
    if (w0 > 0 && kcount > 0) {
      int j = w0 + t;
      u64 kwv = keepw[j >> 6];
      bool alive = (kwv >> (j & 63)) & 1ull;
      if (alive) {
        float4 jb = obox[j];
        float jar = fmaxf(jb.z - jb.x, 0.0f) * fmaxf(jb.w - jb.y, 0.0f);
        for (int a = 0; a < kcount; a++) {
          float4 ab = obox[acc[a]];
          float ix1 = fmaxf(ab.x, jb.x), iy1 = fmaxf(ab.y, jb.y);
          float ix2 = fminf(ab.z, jb.z), iy2 = fminf(ab.w, jb.w);
          float iw = fmaxf(ix2 - ix1, 0.0f), ih = fmaxf(iy2 - iy1, 0.0f);
          float inter = iw * ih;
          if (inter > 0.0f) {
            float aar = fmaxf(ab.z - ab.x, 0.0f) * fmaxf(ab.w - ab.y, 0.0f);
            float iou = inter / fmaxf(aar + jar - inter, 1e-9f);
            if (iou > 0.5f) { alive = false; break; }
          }
        }
      }
      u64 bal = __ballot(alive);
      if (lane == 0) keepw[(w0 >> 6) + w] = bal;
      __syncthreads();
    }
    // step2: window-internal suppression bitmask (thread t = row t)
    {
      int rgp = w0 + t;
      bool ralive = (keepw[rgp >> 6] >> (rgp & 63)) & 1ull;
      float4 rb = obox[rgp];
      float rar = fmaxf(rb.z - rb.x, 0.0f) * fmaxf(rb.w - rb.y, 0.0f);
      #pragma unroll
      for (int wd = 0; wd < 4; wd++) {
        u64 m = 0;
        if (ralive) {
          int cb0 = w0 + wd * 64;
          for (int jj = 0; jj < 64; jj++) {
            int cg = cb0 + jj;
            float4 cb = obox[cg];
            float ix1 = fmaxf(rb.x, cb.x), iy1 = fmaxf(rb.y, cb.y);
            float ix2 = fminf(rb.z, cb.z), iy2 = fminf(rb.w, cb.w);
            float iw = fmaxf(ix2 - ix1, 0.0f), ih = fmaxf(iy2 - iy1, 0.0f);
            float inter = iw * ih;
            if (inter > 0.0f && cg > rgp) {
              float car = fmaxf(cb.z - cb.x, 0.0f) * fmaxf(cb.w - cb.y, 0.0f);
              float iou = inter / fmaxf(rar + car - inter, 1e-9f);
              if (iou > 0.5f) m |= (1ull << jj);
            }
          }
        }
        maskb[t][wd] = m;
      }
    }
    __syncthreads();
    // step3: single-wave serial greedy reduce over the window
    if (w == 0) {
      u64 kw0 = keepw[(w0 >> 6) + 0];
      u64 kw1 = keepw[(w0 >> 6) + 1];
      u64 kw2 = keepw[(w0 >> 6) + 2];
      u64 kw3 = keepw[(w0 >> 6) + 3];
      int kc = kcount;
      #pragma unroll
      for (int wq = 0; wq < 4; wq++) {
        u64 cw = (wq == 0) ? kw0 : (wq == 1) ? kw1 : (wq == 2) ? kw2 : kw3;
        if (cw == 0ull) continue;
        for (int rb0 = 0; rb0 < 64 && kc < NDET; rb0 += 4) {
          u64 gbits = (cw >> rb0) & 0xFull;
          int r = wq * 64 + rb0;
          u64 rm0a = maskb[r][0],   rm0b = maskb[r][1],   rm0c = maskb[r][2],   rm0d = maskb[r][3];
          u64 rm1a = maskb[r+1][0], rm1b = maskb[r+1][1], rm1c = maskb[r+1][2], rm1d = maskb[r+1][3];
          u64 rm2a = maskb[r+2][0], rm2b = maskb[r+2][1], rm2c = maskb[r+2][2], rm2d = maskb[r+2][3];
          u64 rm3a = maskb[r+3][0], rm3b = maskb[r+3][1], rm3c = maskb[r+3][2], rm3d = maskb[r+3][3];
          if (gbits == 0ull) continue;
          #pragma unroll
          for (int d = 0; d < 4; d++) {
            u64 cwq = (wq == 0) ? kw0 : (wq == 1) ? kw1 : (wq == 2) ? kw2 : kw3;
            if ((cwq >> (rb0 + d)) & 1ull) {
              if (lane == 0) acc[kc] = w0 + r + d;
              kc++;
              if (kc >= NDET) break;
              u64 ma = (d == 0) ? rm0a : (d == 1) ? rm1a : (d == 2) ? rm2a : rm3a;
              u64 mb = (d == 0) ? rm0b : (d == 1) ? rm1b : (d == 2) ? rm2b : rm3b;
              u64 mc = (d == 0) ? rm0c : (d == 1) ? rm1c : (d == 2) ? rm2c : rm3c;
              u64 md = (d == 0) ? rm0d : (d == 1) ? rm1d : (d == 2) ? rm2d : rm3d;
              kw0 &= ~ma; kw1 &= ~mb; kw2 &= ~mc; kw3 &= ~md;
            }
          }
          cw = (wq == 0) ? kw0 : (wq == 1) ? kw1 : (wq == 2) ? kw2 : kw3;
        }
      }
      if (lane == 0) {
        keepw[(w0 >> 6) + 0] = kw0;
        keepw[(w0 >> 6) + 1] = kw1;
        keepw[(w0 >> 6) + 2] = kw2;
        keepw[(w0 >> 6) + 3] = kw3;
        kcnt_sh = kc;
      }
    }
    __syncthreads();
    kcount = kcnt_sh;
  }

  // rare path: fewer than 100 kept -> backfill non-kept ascending
  if (t == 0 && kcount < NDET) {
    int run = kcount;
    for (int wq = 0; wq < KPRE / 64 && run < NDET; wq++) {
      u64 nk = ~keepw[wq];
      while (nk && run < NDET) {
        int bit2 = __ffsll((long long)nk) - 1;
        nk &= nk - 1;
        acc[run++] = wq * 64 + bit2;
      }
    }
  }
  __syncthreads();

  if (t < NDET) {
    int k = acc[t];
    bool kept = t < kcount;
    u64 key = accK[k];
    float bx[4]; int label; float sc;
    key_decode(key, b, reg, props, bx, label, sc);
    int oi = b * NDET + t;
    out[(size_t)oi * 4 + 0] = bx[0];
    out[(size_t)oi * 4 + 1] = bx[1];
    out[(size_t)oi * 4 + 2] = bx[2];
    out[(size_t)oi * 4 + 3] = bx[3];
    out[Bn * NDET * 4 + oi] = kept ? sc : -1.0f;
    out[Bn * NDET * 5 + oi] = (float)label;
    out[Bn * NDET * 6 + oi] = kept ? 1.0f : 0.0f;
  }
}

extern "C" void kernel_launch(void* const* d_in, const int* in_sizes, int n_in,
                              void* d_out, int out_size, void* d_ws, size_t ws_size,
                              hipStream_t stream) {
  const float* logits = (const float*)d_in[0];
  const float* reg    = (const float*)d_in[1];
  const float* props  = (const float*)d_in[2];
  float* out = (float*)d_out;
  char* ws = (char*)d_ws;

  u64* keys  = (u64*)(ws + OFF_KEYS);
  u64* slist = (u64*)(ws + OFF_SLIST);
  int* scnt  = (int*)(ws + OFF_SCNT);

  k1_score<<<(Bn * Pn) / 4, 256, 0, stream>>>(logits, reg, props, keys);
  k2_section<<<Bn * NSEC, 256, 0, stream>>>(keys, slist, scnt);
  k3_merge_nms<<<Bn, 256, 0, stream>>>(slist, scnt, reg, props, out);
}